// Round 9
// baseline (924.016 us; speedup 1.0000x reference)
//
#include <hip/hip_runtime.h>
#include <hip/hip_cooperative_groups.h>
#include <cstdint>
#include <cstddef>

namespace cg = cooperative_groups;

#define N_NODES 50000
#define N_EDGES 800000
#define F_IN    512
#define H_DIM   128
#define C_OUT   40
#define TOT_E   (N_EDGES + N_NODES)
#define KTOT    640             // P rows: h | u1 | u2 | u3 | u4
#define ZW      240             // Z cols: 5 blocks x 48
#define NZP     256             // Wzt rows padded to 256

typedef __attribute__((ext_vector_type(8))) __bf16 bf16x8;
typedef __attribute__((ext_vector_type(4))) float f32x4;

__device__ __forceinline__ unsigned short bf16_rne(float f) {
  unsigned int u = __float_as_uint(f);
  u += 0x7fffu + ((u >> 16) & 1u);
  return (unsigned short)(u >> 16);
}
__device__ __forceinline__ float bf16_lo_f(unsigned int u) { return __uint_as_float(u << 16); }
__device__ __forceinline__ float bf16_hi_f(unsigned int u) { return __uint_as_float(u & 0xffff0000u); }

// async global->LDS, 16B per lane; dest must be linear (base + lane*16)
#define GLOAD_LDS16(gp, lp)                                                        \
  __builtin_amdgcn_global_load_lds(                                                \
      (const __attribute__((address_space(1))) void*)(gp),                         \
      (__attribute__((address_space(3))) void*)(lp), 16, 0, 0)

// ----------------------------- setup kernels -------------------------------
// Single u64 atomic per edge: bits [40..63] = count, [0..39] = 2^-24 fixed-pt
// weighted degree. Returned old count = slot of edge in its dst bucket.

__global__ void edge_pass1_k(const int* __restrict__ dst, const float* __restrict__ ew,
                             unsigned long long* __restrict__ acc,
                             int* __restrict__ pos, int e) {
  int i = blockIdx.x * blockDim.x + threadIdx.x;
  if (i < e) {
    int d = dst[i];
    unsigned long long v = (1ull << 40) |
        (unsigned long long)(ew[i] * 16777216.0f + 0.5f);
    unsigned long long old = atomicAdd(&acc[d], v);
    pos[i] = (int)(old >> 40);
  }
}

__global__ void node_pass_k(const unsigned long long* __restrict__ acc,
                            float* __restrict__ dinv, int* __restrict__ cnt, int n) {
  int i = blockIdx.x * blockDim.x + threadIdx.x;
  if (i < n) {
    unsigned long long a = acc[i];
    double dfix = (double)(a & 0xFFFFFFFFFFull);
    float deg = (float)(dfix * (1.0 / 16777216.0) + 1.0);   // +1 self-loop
    dinv[i] = rsqrtf(deg);
    cnt[i] = (int)(a >> 40) + 1;                            // +1 self-loop
  }
}

__global__ __launch_bounds__(256) void block_reduce_k(const int* __restrict__ cnt,
                                                      int* bsum, int n) {
  __shared__ int s[256];
  int t = threadIdx.x;
  int i = blockIdx.x * 256 + t;
  s[t] = (i < n) ? cnt[i] : 0;
  __syncthreads();
  for (int off = 128; off; off >>= 1) {
    if (t < off) s[t] += s[t + off];
    __syncthreads();
  }
  if (t == 0) bsum[blockIdx.x] = s[0];
}

__global__ __launch_bounds__(256) void scan_bsums_k(int* bsum, int nb) {
  __shared__ int s[256];
  int t = threadIdx.x;
  s[t] = (t < nb) ? bsum[t] : 0;
  __syncthreads();
  for (int off = 1; off < 256; off <<= 1) {
    int v = (t >= off) ? s[t - off] : 0;
    __syncthreads();
    s[t] += v;
    __syncthreads();
  }
  if (t < nb) bsum[t] = (t == 0) ? 0 : s[t - 1];
}

__global__ __launch_bounds__(256) void scan_write_k(const int* __restrict__ cnt,
                                                    const int* __restrict__ bsum,
                                                    int* row_ptr, int n) {
  __shared__ int s[256];
  int t = threadIdx.x;
  int i = blockIdx.x * 256 + t;
  int c = (i < n) ? cnt[i] : 0;
  s[t] = c;
  __syncthreads();
  for (int off = 1; off < 256; off <<= 1) {
    int v = (t >= off) ? s[t - off] : 0;
    __syncthreads();
    s[t] += v;
    __syncthreads();
  }
  int ex = bsum[blockIdx.x] + ((t == 0) ? 0 : s[t - 1]);
  if (i < n) row_ptr[i] = ex;
  if (i == n - 1) row_ptr[n] = ex + c;
}

__global__ void scatter2_k(const int* __restrict__ src, const int* __restrict__ dst,
                           const float* __restrict__ ew, const int* __restrict__ pos,
                           const float* __restrict__ dinv, const int* __restrict__ rowp,
                           int2* __restrict__ csr, int e, int n) {
  int i = blockIdx.x * blockDim.x + threadIdx.x;
  if (i < e) {
    int s = src[i], d = dst[i];
    float w = dinv[s] * ew[i] * dinv[d];
    csr[rowp[d] + pos[i]] = make_int2(s, __float_as_int(w));
  } else if (i < e + n) {
    int v = i - e;
    float di = dinv[v];
    csr[rowp[v + 1] - 1] = make_int2(v, __float_as_int(di * di));  // self-loop last
  }
}

// ---- weight-chain precompute: P slices [48 cols x KTOT rows] f32 + rank-1 -
__global__ __launch_bounds__(256) void chains_k(
    const float* __restrict__ W_gcn, const float* __restrict__ b_gcn,
    const float* __restrict__ W_out, const float* __restrict__ b_out,
    float* __restrict__ Pf, float* __restrict__ rv) {
  __shared__ float T0[128 * 4];
  __shared__ float T1[128 * 4];
  const int b = blockIdx.y;          // 0..3
  const int j = b + 1;
  const int c0 = blockIdx.x * 4;     // col group base
  const int ks_all[4][4] = {{0, -1, -1, -1}, {1, 2, -1, -1}, {3, 4, 5, -1}, {6, 7, 8, 9}};
  const int t = threadIdx.x;
  const int lane = t & 63;
  const int wv = t >> 6;             // wave 0..3

  for (int idx = t; idx < 512; idx += 256) {
    int r = idx >> 2, c = idx & 3;
    T0[idx] = W_out[(size_t)(j * 128 + r) * 40 + c0 + c];
  }
  __syncthreads();
  float* Tc = T0;
  float* Tn = T1;
  for (int step = 0; step < j; ++step) {
    int kw = ks_all[b][j - 1 - step];
    {
      float s = b_gcn[kw * 128 + lane] * Tc[lane * 4 + wv] +
                b_gcn[kw * 128 + 64 + lane] * Tc[(64 + lane) * 4 + wv];
      for (int o = 32; o; o >>= 1) s += __shfl_down(s, o);
      if (lane == 0) atomicAdd(&rv[step * 40 + c0 + wv], s);
    }
    const float* W = W_gcn + (size_t)kw * 128 * 128;
    int r = t & 127;
    int ch = (t >> 7) << 1;          // 0 or 2
    float a0 = 0.f, a1 = 0.f;
    for (int k = 0; k < 128; k += 4) {
      float4 w4 = *(const float4*)&W[(size_t)r * 128 + k];
      a0 += w4.x * Tc[(k + 0) * 4 + ch] + w4.y * Tc[(k + 1) * 4 + ch] +
            w4.z * Tc[(k + 2) * 4 + ch] + w4.w * Tc[(k + 3) * 4 + ch];
      a1 += w4.x * Tc[(k + 0) * 4 + ch + 1] + w4.y * Tc[(k + 1) * 4 + ch + 1] +
            w4.z * Tc[(k + 2) * 4 + ch + 1] + w4.w * Tc[(k + 3) * 4 + ch + 1];
    }
    Tn[r * 4 + ch] = a0;
    Tn[r * 4 + ch + 1] = a1;
    __syncthreads();
    float* tmp = Tc; Tc = Tn; Tn = tmp;
  }
  for (int idx = t; idx < 512; idx += 256) {
    int r = idx >> 2, c = idx & 3;
    Pf[(size_t)(c0 + c) * KTOT + j * 128 + r] = Tc[idx];
  }
  if (b == 0) {
    for (int idx = t; idx < 512; idx += 256) {
      int r = idx >> 2, c = idx & 3;
      Pf[(size_t)(c0 + c) * KTOT + r] = W_out[(size_t)r * 40 + c0 + c];
    }
    if (blockIdx.x == 0 && t < 40) atomicAdd(&rv[t], b_out[t]);   // row_1 += b_out
  }
}

// ---- Wz collapse: Wzt[n][k] = bf16( sum_m W_in[k][m] * P(m,n) ), n=j*48+c --
// Also cz[n] = b_in . Pcol + rv[j][c]  (rank-1 bias terms fold into z_j).
__global__ __launch_bounds__(256) void wz_k(
    const float* __restrict__ W_in, const float* __restrict__ b_in,
    const float* __restrict__ Pf, const float* __restrict__ rv,
    unsigned short* __restrict__ Wzt, float* __restrict__ cz) {
  __shared__ float Pcol[128];
  __shared__ float bred[64];
  const int n = blockIdx.x;          // 0..239
  const int j = n / 48, c = n - j * 48;
  const int t = threadIdx.x;
  if (t < 128) Pcol[t] = Pf[(size_t)c * KTOT + j * 128 + t];
  __syncthreads();
  for (int k = t; k < F_IN; k += 256) {
    const float* wr = W_in + (size_t)k * 128;
    float s = 0.f;
    for (int m = 0; m < 128; m += 4) {
      float4 w4 = *(const float4*)&wr[m];
      s += w4.x * Pcol[m] + w4.y * Pcol[m + 1] +
           w4.z * Pcol[m + 2] + w4.w * Pcol[m + 3];
    }
    Wzt[(size_t)n * F_IN + k] = bf16_rne(s);
  }
  if (t < 64) bred[t] = b_in[t] * Pcol[t] + b_in[t + 64] * Pcol[t + 64];
  __syncthreads();
  if (t == 0) {
    float s = 0.f;
    for (int i = 0; i < 64; ++i) s += bred[i];
    float r = (j < 4 && c < 40) ? rv[j * 40 + c] : 0.f;
    cz[n] = s + r;
  }
}

// ------------- fused GEMM: Z = bf16(x @ Wzt + cz), block-planar -----------
// R8/R4/R5 fastest-measured config, frozen: 64x256 tile, BK=32, NT=16,
// 40KB LDS -> 4 blocks/CU, grid 782 co-resident. A reg-staged to bf16;
// B via global_load_lds with pre-swizzled source. Z stored block-planar
// [5][N][48] for Horner-pass gather locality.
__global__ __launch_bounds__(256)
__attribute__((amdgpu_waves_per_eu(4, 4)))
void gemm_xz_k(
    const float* __restrict__ A, const unsigned short* __restrict__ Wzt,
    const float* __restrict__ cz, unsigned short* __restrict__ Z, int M) {
  constexpr int K = F_IN, BK = 32, NT = K / BK;   // 16 k-stages
  __shared__ __align__(16) unsigned short As[2][64][32];  //  8 KB (bf16)
  __shared__ __align__(16) unsigned short Bs[2][256][32]; // 32 KB
  const int t = threadIdx.x;
  const int lane = t & 63;
  const int w = t >> 6;
  const int q = lane >> 4;
  const int l15 = lane & 15;
  const int wm = w >> 1, wn = w & 1;
  const int m0 = blockIdx.x * 64;

  // ---- A staging map: lane -> (row, 8-f32 chunk) ----
  const int ar = w * 16 + (lane >> 2);       // row 0..63
  const int ac = lane & 3;                   // 8-f32 chunk 0..3
  int gm = m0 + ar; if (gm >= M) gm = M - 1;
  const float* pA = A + (size_t)gm * K + (ac << 3);
  const int asw = (ac ^ (ar & 3)) << 3;      // swizzled bf16-slot offset in row

  // ---- B: per-lane pre-swizzled global source pointers (linear LDS dest) --
  const unsigned short* pB[4];
#pragma unroll
  for (int it = 0; it < 4; ++it) {
    int r = (w * 4 + it) * 16 + (lane >> 2);
    int c = lane & 3;
    pB[it] = Wzt + (size_t)r * K + ((c ^ (r & 3)) << 3);
  }

  f32x4 acc[2][8];
#pragma unroll
  for (int i = 0; i < 2; ++i)
#pragma unroll
    for (int j = 0; j < 8; ++j) acc[i][j] = (f32x4){0.f, 0.f, 0.f, 0.f};

  auto STAGE_B = [&](int buf, int ks) {
#pragma unroll
    for (int it = 0; it < 4; ++it)
      GLOAD_LDS16(pB[it] + ks * BK, &Bs[buf][(w * 4 + it) * 16][0] + lane * 8);
  };

  auto COMPUTE = [&](int buf) {
    bf16x8 af[2];
#pragma unroll
    for (int i = 0; i < 2; ++i) {
      int m = (wm << 5) + (i << 4) + l15;
      af[i] = *(const bf16x8*)&As[buf][m][(q ^ (m & 3)) << 3];
    }
#pragma unroll
    for (int j = 0; j < 8; ++j) {
      int nn = (wn << 7) + (j << 4) + l15;
      bf16x8 bfr = *(const bf16x8*)&Bs[buf][nn][(q ^ (nn & 3)) << 3];
#pragma unroll
      for (int i = 0; i < 2; ++i)
        acc[i][j] = __builtin_amdgcn_mfma_f32_16x16x32_bf16(af[i], bfr, acc[i][j], 0, 0, 0);
    }
  };

  // ---- prologue: A(0) regs + B(0) lds in flight (order: A older than B) ---
  float4 fa0 = *(const float4*)(pA + 0);
  float4 fa1 = *(const float4*)(pA + 4);
  STAGE_B(0, 0);

#pragma unroll
  for (int ts = 0; ts < NT; ++ts) {
    // cvt A(ts) (compiler inserts the vmcnt wait for fa0/fa1 here)
    uint4 ua;
    ua.x = (unsigned int)bf16_rne(fa0.x) | ((unsigned int)bf16_rne(fa0.y) << 16);
    ua.y = (unsigned int)bf16_rne(fa0.z) | ((unsigned int)bf16_rne(fa0.w) << 16);
    ua.z = (unsigned int)bf16_rne(fa1.x) | ((unsigned int)bf16_rne(fa1.y) << 16);
    ua.w = (unsigned int)bf16_rne(fa1.z) | ((unsigned int)bf16_rne(fa1.w) << 16);
    // issue A(ts+1) reg loads
    if (ts + 1 < NT) {
      const float* p = pA + (ts + 1) * BK;
      fa0 = *(const float4*)(p + 0);
      fa1 = *(const float4*)(p + 4);
    }
    // swizzled ds_write of A(ts) bf16
    *(uint4*)&As[ts & 1][ar][asw] = ua;
    if (ts + 1 < NT) {
      STAGE_B((ts + 1) & 1, ts + 1);                    // issue BEFORE wait
      asm volatile("s_waitcnt vmcnt(6)" ::: "memory");  // B(ts) landed; 6 fly
    } else {
      asm volatile("s_waitcnt vmcnt(0)" ::: "memory");  // drain last B
    }
    asm volatile("s_waitcnt lgkmcnt(0)" ::: "memory");  // ds_writes retired
    __builtin_amdgcn_s_barrier();
    __builtin_amdgcn_sched_barrier(0);   // no ds_read hoists above the barrier
    COMPUTE(ts & 1);
    __builtin_amdgcn_sched_barrier(0);
    __builtin_amdgcn_s_barrier();        // compute done before buf reuse
  }

  // epilogue: add cz, cast, store BLOCK-PLANAR: Z[(b*N + row)*48 + c]
#pragma unroll
  for (int j = 0; j < 8; ++j) {
    int gcol = (wn << 7) + (j << 4) + l15;
    if (gcol >= ZW) continue;
    float bv = cz[gcol];
    int zb = gcol / 48;
    int zc = gcol - zb * 48;
#pragma unroll
    for (int i = 0; i < 2; ++i) {
      int rb = m0 + (wm << 5) + (i << 4) + (q << 2);
#pragma unroll
      for (int r = 0; r < 4; ++r) {
        int row = rb + r;
        if (row < M)
          Z[((size_t)zb * N_NODES + row) * 48 + zc] = bf16_rne(acc[i][j][r] + bv);
      }
    }
  }
}

// -------------- fused Horner aggregation (cooperative, 4 passes) -----------
// out = z0 + A(z1 + A(z2 + A(z3 + A z4)))   [z_k = Z plane k, bf16]
// Round-9: the 4 agg2_k launches become ONE persistent cooperative kernel
// with grid.sync() between passes. Inner loop is BIT-IDENTICAL to round-8
// (same batch-8 predication, same FP grouping, same node->lane mapping via
// virtualized block index) -> numerics unchanged. __threadfence() before
// each grid.sync() makes y writes visible across non-coherent XCD L2s.
// Benefits: agg counters finally visible (single ~200us dispatch), 3 launch
// ramps deleted, y stays L2-warm across passes.
template <int RS, bool FINAL>
__device__ __forceinline__ void agg_body(
    const int* __restrict__ rowp, const int2* __restrict__ csr,
    const unsigned int* __restrict__ gsrc,   // row stride RS, +gl applied
    const unsigned int* __restrict__ zpl,    // Z plane, stride 24, +gl applied
    unsigned int* __restrict__ ybout, float* __restrict__ fout,
    int n, int wv, int g, int gl, int gs) {
  for (int blk = blockIdx.x; blk * 12 < n; blk += gs) {
    const int node = ((blk << 2) + wv) * 3 + g;
    const bool alive = (g < 3) && (node < n);
    int beg = 0, end = 0;
    if (alive) { beg = rowp[node]; end = rowp[node + 1]; }
    float ax = 0.f, ay = 0.f;
    int j = beg;
    const int eL = end - 1;             // last valid edge (deg >= 1 always)
    while (__any(j < end)) {
      if (j < end) {
        int i0 = j,             i1 = min(j + 1, eL), i2 = min(j + 2, eL), i3 = min(j + 3, eL);
        int i4 = min(j + 4, eL), i5 = min(j + 5, eL), i6 = min(j + 6, eL), i7 = min(j + 7, eL);
        int2 e0 = csr[i0], e1 = csr[i1], e2 = csr[i2], e3 = csr[i3];
        int2 e4 = csr[i4], e5 = csr[i5], e6 = csr[i6], e7 = csr[i7];
        unsigned int v0 = gsrc[(size_t)e0.x * RS], v1 = gsrc[(size_t)e1.x * RS];
        unsigned int v2 = gsrc[(size_t)e2.x * RS], v3 = gsrc[(size_t)e3.x * RS];
        unsigned int v4 = gsrc[(size_t)e4.x * RS], v5 = gsrc[(size_t)e5.x * RS];
        unsigned int v6 = gsrc[(size_t)e6.x * RS], v7 = gsrc[(size_t)e7.x * RS];
        float w0 = __int_as_float(e0.y);
        float w1 = (j + 1 < end) ? __int_as_float(e1.y) : 0.f;
        float w2 = (j + 2 < end) ? __int_as_float(e2.y) : 0.f;
        float w3 = (j + 3 < end) ? __int_as_float(e3.y) : 0.f;
        float w4 = (j + 4 < end) ? __int_as_float(e4.y) : 0.f;
        float w5 = (j + 5 < end) ? __int_as_float(e5.y) : 0.f;
        float w6 = (j + 6 < end) ? __int_as_float(e6.y) : 0.f;
        float w7 = (j + 7 < end) ? __int_as_float(e7.y) : 0.f;
        ax += w0 * bf16_lo_f(v0) + w1 * bf16_lo_f(v1) +
              w2 * bf16_lo_f(v2) + w3 * bf16_lo_f(v3);
        ay += w0 * bf16_hi_f(v0) + w1 * bf16_hi_f(v1) +
              w2 * bf16_hi_f(v2) + w3 * bf16_hi_f(v3);
        ax += w4 * bf16_lo_f(v4) + w5 * bf16_lo_f(v5) +
              w6 * bf16_lo_f(v6) + w7 * bf16_lo_f(v7);
        ay += w4 * bf16_hi_f(v4) + w5 * bf16_hi_f(v5) +
              w6 * bf16_hi_f(v6) + w7 * bf16_hi_f(v7);
      }
      j += 8;
    }
    if (alive) {
      unsigned int z = zpl[(size_t)node * 24];
      float ox = ax + bf16_lo_f(z);
      float oy = ay + bf16_hi_f(z);
      if (FINAL) {
        float2 o; o.x = ox; o.y = oy;
        *(float2*)&fout[(size_t)node * 40 + (gl << 1)] = o;
      } else {
        ybout[(size_t)node * 20 + gl] =
            (unsigned int)bf16_rne(ox) | ((unsigned int)bf16_rne(oy) << 16);
      }
    }
  }
}

__global__ __launch_bounds__(256)
__attribute__((amdgpu_waves_per_eu(4, 4)))
void agg4_k(const int* __restrict__ rowp, const int2* __restrict__ csr,
            const unsigned int* __restrict__ Zd,
            unsigned int* __restrict__ ya, unsigned int* __restrict__ yb,
            float* __restrict__ out, int n) {
  cg::grid_group grid = cg::this_grid();
  const int lane = threadIdx.x & 63;
  const int wv = threadIdx.x >> 6;
  const int g = lane / 20;            // group 0..2 (g==3: idle)
  const int gl = lane - g * 20;       // 0..19
  const int gs = gridDim.x;

  // pass 0: y1 = A*z4 + z3
  agg_body<24, false>(rowp, csr, Zd + (size_t)4 * N_NODES * 24 + gl,
                      Zd + (size_t)3 * N_NODES * 24 + gl, ya, nullptr,
                      n, wv, g, gl, gs);
  __threadfence(); grid.sync();
  // pass 1: y2 = A*y1 + z2
  agg_body<20, false>(rowp, csr, ya + gl,
                      Zd + (size_t)2 * N_NODES * 24 + gl, yb, nullptr,
                      n, wv, g, gl, gs);
  __threadfence(); grid.sync();
  // pass 2: y3 = A*y2 + z1
  agg_body<20, false>(rowp, csr, yb + gl,
                      Zd + (size_t)1 * N_NODES * 24 + gl, ya, nullptr,
                      n, wv, g, gl, gs);
  __threadfence(); grid.sync();
  // pass 3: out = A*y3 + z0  (f32)
  agg_body<20, true>(rowp, csr, ya + gl,
                     Zd + (size_t)0 * N_NODES * 24 + gl, nullptr, out,
                     n, wv, g, gl, gs);
}

// ------------------------------- launcher ----------------------------------

extern "C" void kernel_launch(void* const* d_in, const int* in_sizes, int n_in,
                              void* d_out, int out_size, void* d_ws, size_t ws_size,
                              hipStream_t stream) {
  const float* x     = (const float*)d_in[0];
  const int*   eidx  = (const int*)  d_in[1];
  const float* ew    = (const float*)d_in[2];
  const float* W_in  = (const float*)d_in[3];
  const float* b_in  = (const float*)d_in[4];
  const float* W_gcn = (const float*)d_in[5];
  const float* b_gcn = (const float*)d_in[6];
  const float* W_out = (const float*)d_in[7];
  const float* b_out = (const float*)d_in[8];
  float* out = (float*)d_out;

  const int* src = eidx;
  const int* dst = eidx + N_EDGES;

  char* ws = (char*)d_ws;
  size_t off = 0;
  auto alloc = [&](size_t bytes) -> void* {
    void* p = ws + off;
    off += (bytes + 255) & ~(size_t)255;
    return p;
  };
  unsigned long long* acc = (unsigned long long*)alloc((size_t)N_NODES * 8);
  int*   pos    = (int*)  alloc((size_t)N_EDGES * 4);
  int*   cnt    = (int*)  alloc((size_t)N_NODES * 4);
  int*   rowp   = (int*)  alloc((size_t)(N_NODES + 1) * 4);
  float* dinv   = (float*)alloc((size_t)N_NODES * 4);
  int*   bsum   = (int*)  alloc((size_t)256 * 4);
  int2*  csr    = (int2*) alloc((size_t)TOT_E * 8);
  float* Pf     = (float*)alloc((size_t)48 * KTOT * 4);
  unsigned short* Wzt = (unsigned short*)alloc((size_t)NZP * F_IN * 2);
  float* cz     = (float*)alloc((size_t)NZP * 4);
  unsigned short* Z = (unsigned short*)alloc((size_t)5 * N_NODES * 48 * 2);
  unsigned int* ya  = (unsigned int*)alloc((size_t)N_NODES * 20 * 4);
  unsigned int* yb  = (unsigned int*)alloc((size_t)N_NODES * 20 * 4);
  float* rv     = (float*)alloc((size_t)4 * 40 * 4);
  (void)ws_size; (void)in_sizes; (void)n_in; (void)out_size;

  dim3 b256(256);
  const int NB = (N_NODES + 255) / 256;
  const int GBZ = (N_NODES + 63) / 64;        // 782 blocks, all co-resident
  const unsigned int* Zd = (const unsigned int*)Z;

  hipMemsetAsync(acc, 0, (size_t)N_NODES * 8, stream);
  hipMemsetAsync(rv, 0, (size_t)4 * 40 * 4, stream);
  hipMemsetAsync(Pf, 0, (size_t)48 * KTOT * 4, stream);   // pad cols 40..47 = 0
  hipMemsetAsync(Wzt, 0, (size_t)NZP * F_IN * 2, stream); // pad rows 240..255 = 0
  hipMemsetAsync(cz, 0, (size_t)NZP * 4, stream);

  edge_pass1_k<<<(N_EDGES + 255) / 256, b256, 0, stream>>>(dst, ew, acc, pos, N_EDGES);
  node_pass_k<<<NB, b256, 0, stream>>>(acc, dinv, cnt, N_NODES);
  block_reduce_k<<<NB, b256, 0, stream>>>(cnt, bsum, N_NODES);
  scan_bsums_k<<<1, b256, 0, stream>>>(bsum, NB);
  scan_write_k<<<NB, b256, 0, stream>>>(cnt, bsum, rowp, N_NODES);
  scatter2_k<<<(TOT_E + 255) / 256, b256, 0, stream>>>(src, dst, ew, pos, dinv, rowp,
                                                       csr, N_EDGES, N_NODES);

  chains_k<<<dim3(10, 4), b256, 0, stream>>>(W_gcn, b_gcn, W_out, b_out, Pf, rv);
  wz_k<<<ZW, b256, 0, stream>>>(W_in, b_in, Pf, rv, Wzt, cz);

  // Z[5][N][48] = bf16(x @ Wzt + cz), block-planar
  gemm_xz_k<<<GBZ, b256, 0, stream>>>(x, Wzt, cz, Z, N_NODES);

  // Horner (fused, cooperative): out = z0 + A(z1 + A(z2 + A(z3 + A z4)))
  {
    const int* rowp_ = rowp; const int2* csr_ = csr;
    const unsigned int* Zd_ = Zd;
    unsigned int* ya_ = ya; unsigned int* yb_ = yb;
    float* out_ = out; int n_ = N_NODES;
    void* kargs[] = {(void*)&rowp_, (void*)&csr_, (void*)&Zd_,
                     (void*)&ya_, (void*)&yb_, (void*)&out_, (void*)&n_};
    hipLaunchCooperativeKernel((const void*)agg4_k, dim3(768), dim3(256),
                               kargs, 0, stream);
  }
}

// Round 10
// 384.928 us; speedup vs baseline: 2.4005x; 2.4005x over previous
//
#include <hip/hip_runtime.h>
#include <cstdint>
#include <cstddef>

#define N_NODES 50000
#define N_EDGES 800000
#define F_IN    512
#define H_DIM   128
#define C_OUT   40
#define TOT_E   (N_EDGES + N_NODES)
#define KTOT    640             // P rows: h | u1 | u2 | u3 | u4
#define ZW      240             // Z cols: 5 blocks x 48
#define NZP     256             // Wzt rows padded to 256

typedef __attribute__((ext_vector_type(8))) __bf16 bf16x8;
typedef __attribute__((ext_vector_type(4))) float f32x4;

__device__ __forceinline__ unsigned short bf16_rne(float f) {
  unsigned int u = __float_as_uint(f);
  u += 0x7fffu + ((u >> 16) & 1u);
  return (unsigned short)(u >> 16);
}
__device__ __forceinline__ float bf16_lo_f(unsigned int u) { return __uint_as_float(u << 16); }
__device__ __forceinline__ float bf16_hi_f(unsigned int u) { return __uint_as_float(u & 0xffff0000u); }
__device__ __forceinline__ unsigned int u4get(const uint4& v, int p) {
  return p == 0 ? v.x : p == 1 ? v.y : p == 2 ? v.z : v.w;
}

// async global->LDS, 16B per lane; dest must be linear (base + lane*16)
#define GLOAD_LDS16(gp, lp)                                                        \
  __builtin_amdgcn_global_load_lds(                                                \
      (const __attribute__((address_space(1))) void*)(gp),                         \
      (__attribute__((address_space(3))) void*)(lp), 16, 0, 0)

// ----------------------------- setup kernels -------------------------------
// Single u64 atomic per edge: bits [40..63] = count, [0..39] = 2^-24 fixed-pt
// weighted degree. Returned old count = slot of edge in its dst bucket.

__global__ void edge_pass1_k(const int* __restrict__ dst, const float* __restrict__ ew,
                             unsigned long long* __restrict__ acc,
                             int* __restrict__ pos, int e) {
  int i = blockIdx.x * blockDim.x + threadIdx.x;
  if (i < e) {
    int d = dst[i];
    unsigned long long v = (1ull << 40) |
        (unsigned long long)(ew[i] * 16777216.0f + 0.5f);
    unsigned long long old = atomicAdd(&acc[d], v);
    pos[i] = (int)(old >> 40);
  }
}

__global__ void node_pass_k(const unsigned long long* __restrict__ acc,
                            float* __restrict__ dinv, int* __restrict__ cnt, int n) {
  int i = blockIdx.x * blockDim.x + threadIdx.x;
  if (i < n) {
    unsigned long long a = acc[i];
    double dfix = (double)(a & 0xFFFFFFFFFFull);
    float deg = (float)(dfix * (1.0 / 16777216.0) + 1.0);   // +1 self-loop
    dinv[i] = rsqrtf(deg);
    cnt[i] = (int)(a >> 40) + 1;                            // +1 self-loop
  }
}

__global__ __launch_bounds__(256) void block_reduce_k(const int* __restrict__ cnt,
                                                      int* bsum, int n) {
  __shared__ int s[256];
  int t = threadIdx.x;
  int i = blockIdx.x * 256 + t;
  s[t] = (i < n) ? cnt[i] : 0;
  __syncthreads();
  for (int off = 128; off; off >>= 1) {
    if (t < off) s[t] += s[t + off];
    __syncthreads();
  }
  if (t == 0) bsum[blockIdx.x] = s[0];
}

__global__ __launch_bounds__(256) void scan_bsums_k(int* bsum, int nb) {
  __shared__ int s[256];
  int t = threadIdx.x;
  s[t] = (t < nb) ? bsum[t] : 0;
  __syncthreads();
  for (int off = 1; off < 256; off <<= 1) {
    int v = (t >= off) ? s[t - off] : 0;
    __syncthreads();
    s[t] += v;
    __syncthreads();
  }
  if (t < nb) bsum[t] = (t == 0) ? 0 : s[t - 1];
}

__global__ __launch_bounds__(256) void scan_write_k(const int* __restrict__ cnt,
                                                    const int* __restrict__ bsum,
                                                    int* row_ptr, int n) {
  __shared__ int s[256];
  int t = threadIdx.x;
  int i = blockIdx.x * 256 + t;
  int c = (i < n) ? cnt[i] : 0;
  s[t] = c;
  __syncthreads();
  for (int off = 1; off < 256; off <<= 1) {
    int v = (t >= off) ? s[t - off] : 0;
    __syncthreads();
    s[t] += v;
    __syncthreads();
  }
  int ex = bsum[blockIdx.x] + ((t == 0) ? 0 : s[t - 1]);
  if (i < n) row_ptr[i] = ex;
  if (i == n - 1) row_ptr[n] = ex + c;
}

__global__ void scatter2_k(const int* __restrict__ src, const int* __restrict__ dst,
                           const float* __restrict__ ew, const int* __restrict__ pos,
                           const float* __restrict__ dinv, const int* __restrict__ rowp,
                           int2* __restrict__ csr, int e, int n) {
  int i = blockIdx.x * blockDim.x + threadIdx.x;
  if (i < e) {
    int s = src[i], d = dst[i];
    float w = dinv[s] * ew[i] * dinv[d];
    csr[rowp[d] + pos[i]] = make_int2(s, __float_as_int(w));
  } else if (i < e + n) {
    int v = i - e;
    float di = dinv[v];
    csr[rowp[v + 1] - 1] = make_int2(v, __float_as_int(di * di));  // self-loop last
  }
}

// ---- weight-chain precompute: P slices [48 cols x KTOT rows] f32 + rank-1 -
__global__ __launch_bounds__(256) void chains_k(
    const float* __restrict__ W_gcn, const float* __restrict__ b_gcn,
    const float* __restrict__ W_out, const float* __restrict__ b_out,
    float* __restrict__ Pf, float* __restrict__ rv) {
  __shared__ float T0[128 * 4];
  __shared__ float T1[128 * 4];
  const int b = blockIdx.y;          // 0..3
  const int j = b + 1;
  const int c0 = blockIdx.x * 4;     // col group base
  const int ks_all[4][4] = {{0, -1, -1, -1}, {1, 2, -1, -1}, {3, 4, 5, -1}, {6, 7, 8, 9}};
  const int t = threadIdx.x;
  const int lane = t & 63;
  const int wv = t >> 6;             // wave 0..3

  for (int idx = t; idx < 512; idx += 256) {
    int r = idx >> 2, c = idx & 3;
    T0[idx] = W_out[(size_t)(j * 128 + r) * 40 + c0 + c];
  }
  __syncthreads();
  float* Tc = T0;
  float* Tn = T1;
  for (int step = 0; step < j; ++step) {
    int kw = ks_all[b][j - 1 - step];
    {
      float s = b_gcn[kw * 128 + lane] * Tc[lane * 4 + wv] +
                b_gcn[kw * 128 + 64 + lane] * Tc[(64 + lane) * 4 + wv];
      for (int o = 32; o; o >>= 1) s += __shfl_down(s, o);
      if (lane == 0) atomicAdd(&rv[step * 40 + c0 + wv], s);
    }
    const float* W = W_gcn + (size_t)kw * 128 * 128;
    int r = t & 127;
    int ch = (t >> 7) << 1;          // 0 or 2
    float a0 = 0.f, a1 = 0.f;
    for (int k = 0; k < 128; k += 4) {
      float4 w4 = *(const float4*)&W[(size_t)r * 128 + k];
      a0 += w4.x * Tc[(k + 0) * 4 + ch] + w4.y * Tc[(k + 1) * 4 + ch] +
            w4.z * Tc[(k + 2) * 4 + ch] + w4.w * Tc[(k + 3) * 4 + ch];
      a1 += w4.x * Tc[(k + 0) * 4 + ch + 1] + w4.y * Tc[(k + 1) * 4 + ch + 1] +
            w4.z * Tc[(k + 2) * 4 + ch + 1] + w4.w * Tc[(k + 3) * 4 + ch + 1];
    }
    Tn[r * 4 + ch] = a0;
    Tn[r * 4 + ch + 1] = a1;
    __syncthreads();
    float* tmp = Tc; Tc = Tn; Tn = tmp;
  }
  for (int idx = t; idx < 512; idx += 256) {
    int r = idx >> 2, c = idx & 3;
    Pf[(size_t)(c0 + c) * KTOT + j * 128 + r] = Tc[idx];
  }
  if (b == 0) {
    for (int idx = t; idx < 512; idx += 256) {
      int r = idx >> 2, c = idx & 3;
      Pf[(size_t)(c0 + c) * KTOT + r] = W_out[(size_t)r * 40 + c0 + c];
    }
    if (blockIdx.x == 0 && t < 40) atomicAdd(&rv[t], b_out[t]);   // row_1 += b_out
  }
}

// ---- Wz collapse: Wzt[n][k] = bf16( sum_m W_in[k][m] * P(m,n) ), n=j*48+c --
// Also cz[n] = b_in . Pcol + rv[j][c]  (rank-1 bias terms fold into z_j).
__global__ __launch_bounds__(256) void wz_k(
    const float* __restrict__ W_in, const float* __restrict__ b_in,
    const float* __restrict__ Pf, const float* __restrict__ rv,
    unsigned short* __restrict__ Wzt, float* __restrict__ cz) {
  __shared__ float Pcol[128];
  __shared__ float bred[64];
  const int n = blockIdx.x;          // 0..239
  const int j = n / 48, c = n - j * 48;
  const int t = threadIdx.x;
  if (t < 128) Pcol[t] = Pf[(size_t)c * KTOT + j * 128 + t];
  __syncthreads();
  for (int k = t; k < F_IN; k += 256) {
    const float* wr = W_in + (size_t)k * 128;
    float s = 0.f;
    for (int m = 0; m < 128; m += 4) {
      float4 w4 = *(const float4*)&wr[m];
      s += w4.x * Pcol[m] + w4.y * Pcol[m + 1] +
           w4.z * Pcol[m + 2] + w4.w * Pcol[m + 3];
    }
    Wzt[(size_t)n * F_IN + k] = bf16_rne(s);
  }
  if (t < 64) bred[t] = b_in[t] * Pcol[t] + b_in[t + 64] * Pcol[t + 64];
  __syncthreads();
  if (t == 0) {
    float s = 0.f;
    for (int i = 0; i < 64; ++i) s += bred[i];
    float r = (j < 4 && c < 40) ? rv[j * 40 + c] : 0.f;
    cz[n] = s + r;
  }
}

// ------------- fused GEMM: Z = bf16(x @ Wzt + cz), block-planar -----------
// R8/R4/R5 fastest-measured config, FROZEN: 64x256 tile, BK=32, NT=16,
// 40KB LDS -> 4 blocks/CU, grid 782 co-resident. A reg-staged to bf16;
// B via global_load_lds with pre-swizzled source. Z stored block-planar
// [5][N][48] for Horner-pass gather locality.
__global__ __launch_bounds__(256)
__attribute__((amdgpu_waves_per_eu(4, 4)))
void gemm_xz_k(
    const float* __restrict__ A, const unsigned short* __restrict__ Wzt,
    const float* __restrict__ cz, unsigned short* __restrict__ Z, int M) {
  constexpr int K = F_IN, BK = 32, NT = K / BK;   // 16 k-stages
  __shared__ __align__(16) unsigned short As[2][64][32];  //  8 KB (bf16)
  __shared__ __align__(16) unsigned short Bs[2][256][32]; // 32 KB
  const int t = threadIdx.x;
  const int lane = t & 63;
  const int w = t >> 6;
  const int q = lane >> 4;
  const int l15 = lane & 15;
  const int wm = w >> 1, wn = w & 1;
  const int m0 = blockIdx.x * 64;

  // ---- A staging map: lane -> (row, 8-f32 chunk) ----
  const int ar = w * 16 + (lane >> 2);       // row 0..63
  const int ac = lane & 3;                   // 8-f32 chunk 0..3
  int gm = m0 + ar; if (gm >= M) gm = M - 1;
  const float* pA = A + (size_t)gm * K + (ac << 3);
  const int asw = (ac ^ (ar & 3)) << 3;      // swizzled bf16-slot offset in row

  // ---- B: per-lane pre-swizzled global source pointers (linear LDS dest) --
  const unsigned short* pB[4];
#pragma unroll
  for (int it = 0; it < 4; ++it) {
    int r = (w * 4 + it) * 16 + (lane >> 2);
    int c = lane & 3;
    pB[it] = Wzt + (size_t)r * K + ((c ^ (r & 3)) << 3);
  }

  f32x4 acc[2][8];
#pragma unroll
  for (int i = 0; i < 2; ++i)
#pragma unroll
    for (int j = 0; j < 8; ++j) acc[i][j] = (f32x4){0.f, 0.f, 0.f, 0.f};

  auto STAGE_B = [&](int buf, int ks) {
#pragma unroll
    for (int it = 0; it < 4; ++it)
      GLOAD_LDS16(pB[it] + ks * BK, &Bs[buf][(w * 4 + it) * 16][0] + lane * 8);
  };

  auto COMPUTE = [&](int buf) {
    bf16x8 af[2];
#pragma unroll
    for (int i = 0; i < 2; ++i) {
      int m = (wm << 5) + (i << 4) + l15;
      af[i] = *(const bf16x8*)&As[buf][m][(q ^ (m & 3)) << 3];
    }
#pragma unroll
    for (int j = 0; j < 8; ++j) {
      int nn = (wn << 7) + (j << 4) + l15;
      bf16x8 bfr = *(const bf16x8*)&Bs[buf][nn][(q ^ (nn & 3)) << 3];
#pragma unroll
      for (int i = 0; i < 2; ++i)
        acc[i][j] = __builtin_amdgcn_mfma_f32_16x16x32_bf16(af[i], bfr, acc[i][j], 0, 0, 0);
    }
  };

  // ---- prologue: A(0) regs + B(0) lds in flight (order: A older than B) ---
  float4 fa0 = *(const float4*)(pA + 0);
  float4 fa1 = *(const float4*)(pA + 4);
  STAGE_B(0, 0);

#pragma unroll
  for (int ts = 0; ts < NT; ++ts) {
    // cvt A(ts) (compiler inserts the vmcnt wait for fa0/fa1 here)
    uint4 ua;
    ua.x = (unsigned int)bf16_rne(fa0.x) | ((unsigned int)bf16_rne(fa0.y) << 16);
    ua.y = (unsigned int)bf16_rne(fa0.z) | ((unsigned int)bf16_rne(fa0.w) << 16);
    ua.z = (unsigned int)bf16_rne(fa1.x) | ((unsigned int)bf16_rne(fa1.y) << 16);
    ua.w = (unsigned int)bf16_rne(fa1.z) | ((unsigned int)bf16_rne(fa1.w) << 16);
    // issue A(ts+1) reg loads
    if (ts + 1 < NT) {
      const float* p = pA + (ts + 1) * BK;
      fa0 = *(const float4*)(p + 0);
      fa1 = *(const float4*)(p + 4);
    }
    // swizzled ds_write of A(ts) bf16
    *(uint4*)&As[ts & 1][ar][asw] = ua;
    if (ts + 1 < NT) {
      STAGE_B((ts + 1) & 1, ts + 1);                    // issue BEFORE wait
      asm volatile("s_waitcnt vmcnt(6)" ::: "memory");  // B(ts) landed; 6 fly
    } else {
      asm volatile("s_waitcnt vmcnt(0)" ::: "memory");  // drain last B
    }
    asm volatile("s_waitcnt lgkmcnt(0)" ::: "memory");  // ds_writes retired
    __builtin_amdgcn_s_barrier();
    __builtin_amdgcn_sched_barrier(0);   // no ds_read hoists above the barrier
    COMPUTE(ts & 1);
    __builtin_amdgcn_sched_barrier(0);
    __builtin_amdgcn_s_barrier();        // compute done before buf reuse
  }

  // epilogue: add cz, cast, store BLOCK-PLANAR: Z[(b*N + row)*48 + c]
#pragma unroll
  for (int j = 0; j < 8; ++j) {
    int gcol = (wn << 7) + (j << 4) + l15;
    if (gcol >= ZW) continue;
    float bv = cz[gcol];
    int zb = gcol / 48;
    int zc = gcol - zb * 48;
#pragma unroll
    for (int i = 0; i < 2; ++i) {
      int rb = m0 + (wm << 5) + (i << 4) + (q << 2);
#pragma unroll
      for (int r = 0; r < 4; ++r) {
        int row = rb + r;
        if (row < M)
          Z[((size_t)zb * N_NODES + row) * 48 + zc] = bf16_rne(acc[i][j][r] + bv);
      }
    }
  }
}

// ---------------- Horner aggregation over 40-wide z blocks -----------------
// out = z0 + A(z1 + A(z2 + A(z3 + A z4)))   [z_k = Z plane k, bf16]
// PASS 0: y1 = A*z4 + z3   PASS 1: y2 = A*y1 + z2
// PASS 2: y3 = A*y2 + z1   PASS 3: out = A*y3 + z0
// Round-10: back to SEPARATE launches (R9's cooperative fusion capped
// instantaneous parallelism at 3 blocks/CU -> 3x slower; block turnover IS
// the occupancy mechanism for latency-bound gathers). R9's counters showed
// agg is issue/latency-bound (BW 3%, VALU 5%) -> cut per-edge instruction
// count 4x: each 5-lane group gathers a full 80B row as ONE dwordx4/lane,
// 12 nodes per wave (was 3 nodes with 20x dword loads). Rows are 16B
// aligned (y stride 80B, Z stride 96B). Per-column accumulation tree is
// BIT-IDENTICAL to round-8 (batch-8, two groups of 4, w=0 padding).
// waves_per_eu(4,4): RA budget 128 VGPR (body ~90, no spill), 4 blocks/CU
// -> 1024 of 1042 blocks co-resident.
template <int PASS>
__global__ __launch_bounds__(256)
__attribute__((amdgpu_waves_per_eu(4, 4)))
void agg2_k(
    const int* __restrict__ rowp, const int2* __restrict__ csr,
    const unsigned int* __restrict__ yin,   // bf16-pair rows [N][20] (PASS>=1)
    const unsigned int* __restrict__ Zd,    // block-planar Z dwords [5][N][24]
    unsigned int* __restrict__ ybout,       // bf16-pair rows [N][20] (PASS<3)
    float* __restrict__ fout, int n) {
  const int lane = threadIdx.x & 63;
  const int wv = threadIdx.x >> 6;
  const int g = lane / 5;             // group 0..11 (g==12: lanes 60-63 idle)
  const int gl = lane - g * 5;        // 0..4 (dwordx4-slot within row)
  const int go = gl << 2;             // dword offset within row
  const int node = ((blockIdx.x << 2) + wv) * 12 + g;
  const bool alive = (g < 12) && (node < n);
  int beg = 0, end = 0;
  if (alive) { beg = rowp[node]; end = rowp[node + 1]; }
  float ax[4] = {0.f, 0.f, 0.f, 0.f};
  float ay[4] = {0.f, 0.f, 0.f, 0.f};
  int j = beg;
  const int eL = end - 1;             // last valid edge (deg >= 1 always)
  constexpr int RS = (PASS == 0) ? 24 : 20;
  const unsigned int* gsrc =
      (PASS == 0) ? (Zd + (size_t)4 * N_NODES * 24) : yin;
  while (__any(j < end)) {
    if (j < end) {
      int i0 = j,             i1 = min(j + 1, eL), i2 = min(j + 2, eL), i3 = min(j + 3, eL);
      int i4 = min(j + 4, eL), i5 = min(j + 5, eL), i6 = min(j + 6, eL), i7 = min(j + 7, eL);
      int2 e0 = csr[i0], e1 = csr[i1], e2 = csr[i2], e3 = csr[i3];
      int2 e4 = csr[i4], e5 = csr[i5], e6 = csr[i6], e7 = csr[i7];
      uint4 V0 = *(const uint4*)&gsrc[(size_t)e0.x * RS + go];
      uint4 V1 = *(const uint4*)&gsrc[(size_t)e1.x * RS + go];
      uint4 V2 = *(const uint4*)&gsrc[(size_t)e2.x * RS + go];
      uint4 V3 = *(const uint4*)&gsrc[(size_t)e3.x * RS + go];
      uint4 V4 = *(const uint4*)&gsrc[(size_t)e4.x * RS + go];
      uint4 V5 = *(const uint4*)&gsrc[(size_t)e5.x * RS + go];
      uint4 V6 = *(const uint4*)&gsrc[(size_t)e6.x * RS + go];
      uint4 V7 = *(const uint4*)&gsrc[(size_t)e7.x * RS + go];
      float w0 = __int_as_float(e0.y);
      float w1 = (j + 1 < end) ? __int_as_float(e1.y) : 0.f;
      float w2 = (j + 2 < end) ? __int_as_float(e2.y) : 0.f;
      float w3 = (j + 3 < end) ? __int_as_float(e3.y) : 0.f;
      float w4 = (j + 4 < end) ? __int_as_float(e4.y) : 0.f;
      float w5 = (j + 5 < end) ? __int_as_float(e5.y) : 0.f;
      float w6 = (j + 6 < end) ? __int_as_float(e6.y) : 0.f;
      float w7 = (j + 7 < end) ? __int_as_float(e7.y) : 0.f;
#pragma unroll
      for (int p = 0; p < 4; ++p) {
        unsigned int v0 = u4get(V0, p), v1 = u4get(V1, p);
        unsigned int v2 = u4get(V2, p), v3 = u4get(V3, p);
        unsigned int v4 = u4get(V4, p), v5 = u4get(V5, p);
        unsigned int v6 = u4get(V6, p), v7 = u4get(V7, p);
        ax[p] += w0 * bf16_lo_f(v0) + w1 * bf16_lo_f(v1) +
                 w2 * bf16_lo_f(v2) + w3 * bf16_lo_f(v3);
        ay[p] += w0 * bf16_hi_f(v0) + w1 * bf16_hi_f(v1) +
                 w2 * bf16_hi_f(v2) + w3 * bf16_hi_f(v3);
        ax[p] += w4 * bf16_lo_f(v4) + w5 * bf16_lo_f(v5) +
                 w6 * bf16_lo_f(v6) + w7 * bf16_lo_f(v7);
        ay[p] += w4 * bf16_hi_f(v4) + w5 * bf16_hi_f(v5) +
                 w6 * bf16_hi_f(v6) + w7 * bf16_hi_f(v7);
      }
    }
    j += 8;
  }
  if (alive) {
    uint4 z = *(const uint4*)&Zd[((size_t)(3 - PASS) * N_NODES + node) * 24 + go];
    float ox[4], oy[4];
#pragma unroll
    for (int p = 0; p < 4; ++p) {
      unsigned int zp = u4get(z, p);
      ox[p] = ax[p] + bf16_lo_f(zp);
      oy[p] = ay[p] + bf16_hi_f(zp);
    }
    if (PASS == 3) {
      float4 f0; f0.x = ox[0]; f0.y = oy[0]; f0.z = ox[1]; f0.w = oy[1];
      float4 f1; f1.x = ox[2]; f1.y = oy[2]; f1.z = ox[3]; f1.w = oy[3];
      *(float4*)&fout[(size_t)node * 40 + (gl << 3)] = f0;
      *(float4*)&fout[(size_t)node * 40 + (gl << 3) + 4] = f1;
    } else {
      uint4 o;
      o.x = (unsigned int)bf16_rne(ox[0]) | ((unsigned int)bf16_rne(oy[0]) << 16);
      o.y = (unsigned int)bf16_rne(ox[1]) | ((unsigned int)bf16_rne(oy[1]) << 16);
      o.z = (unsigned int)bf16_rne(ox[2]) | ((unsigned int)bf16_rne(oy[2]) << 16);
      o.w = (unsigned int)bf16_rne(ox[3]) | ((unsigned int)bf16_rne(oy[3]) << 16);
      *(uint4*)&ybout[(size_t)node * 20 + go] = o;
    }
  }
}

// ------------------------------- launcher ----------------------------------

extern "C" void kernel_launch(void* const* d_in, const int* in_sizes, int n_in,
                              void* d_out, int out_size, void* d_ws, size_t ws_size,
                              hipStream_t stream) {
  const float* x     = (const float*)d_in[0];
  const int*   eidx  = (const int*)  d_in[1];
  const float* ew    = (const float*)d_in[2];
  const float* W_in  = (const float*)d_in[3];
  const float* b_in  = (const float*)d_in[4];
  const float* W_gcn = (const float*)d_in[5];
  const float* b_gcn = (const float*)d_in[6];
  const float* W_out = (const float*)d_in[7];
  const float* b_out = (const float*)d_in[8];
  float* out = (float*)d_out;

  const int* src = eidx;
  const int* dst = eidx + N_EDGES;

  char* ws = (char*)d_ws;
  size_t off = 0;
  auto alloc = [&](size_t bytes) -> void* {
    void* p = ws + off;
    off += (bytes + 255) & ~(size_t)255;
    return p;
  };
  unsigned long long* acc = (unsigned long long*)alloc((size_t)N_NODES * 8);
  int*   pos    = (int*)  alloc((size_t)N_EDGES * 4);
  int*   cnt    = (int*)  alloc((size_t)N_NODES * 4);
  int*   rowp   = (int*)  alloc((size_t)(N_NODES + 1) * 4);
  float* dinv   = (float*)alloc((size_t)N_NODES * 4);
  int*   bsum   = (int*)  alloc((size_t)256 * 4);
  int2*  csr    = (int2*) alloc((size_t)TOT_E * 8);
  float* Pf     = (float*)alloc((size_t)48 * KTOT * 4);
  unsigned short* Wzt = (unsigned short*)alloc((size_t)NZP * F_IN * 2);
  float* cz     = (float*)alloc((size_t)NZP * 4);
  unsigned short* Z = (unsigned short*)alloc((size_t)5 * N_NODES * 48 * 2);
  unsigned int* ya  = (unsigned int*)alloc((size_t)N_NODES * 20 * 4);
  unsigned int* yb  = (unsigned int*)alloc((size_t)N_NODES * 20 * 4);
  float* rv     = (float*)alloc((size_t)4 * 40 * 4);
  (void)ws_size; (void)in_sizes; (void)n_in; (void)out_size;

  dim3 b256(256);
  const int NB = (N_NODES + 255) / 256;
  const int GBZ = (N_NODES + 63) / 64;        // 782 blocks, all co-resident
  const int AB12 = (N_NODES + 47) / 48;       // 1042 blocks (48 nodes each)
  const unsigned int* Zd = (const unsigned int*)Z;

  hipMemsetAsync(acc, 0, (size_t)N_NODES * 8, stream);
  hipMemsetAsync(rv, 0, (size_t)4 * 40 * 4, stream);
  hipMemsetAsync(Pf, 0, (size_t)48 * KTOT * 4, stream);   // pad cols 40..47 = 0
  hipMemsetAsync(Wzt, 0, (size_t)NZP * F_IN * 2, stream); // pad rows 240..255 = 0
  hipMemsetAsync(cz, 0, (size_t)NZP * 4, stream);

  edge_pass1_k<<<(N_EDGES + 255) / 256, b256, 0, stream>>>(dst, ew, acc, pos, N_EDGES);
  node_pass_k<<<NB, b256, 0, stream>>>(acc, dinv, cnt, N_NODES);
  block_reduce_k<<<NB, b256, 0, stream>>>(cnt, bsum, N_NODES);
  scan_bsums_k<<<1, b256, 0, stream>>>(bsum, NB);
  scan_write_k<<<NB, b256, 0, stream>>>(cnt, bsum, rowp, N_NODES);
  scatter2_k<<<(TOT_E + 255) / 256, b256, 0, stream>>>(src, dst, ew, pos, dinv, rowp,
                                                       csr, N_EDGES, N_NODES);

  chains_k<<<dim3(10, 4), b256, 0, stream>>>(W_gcn, b_gcn, W_out, b_out, Pf, rv);
  wz_k<<<ZW, b256, 0, stream>>>(W_in, b_in, Pf, rv, Wzt, cz);

  // Z[5][N][48] = bf16(x @ Wzt + cz), block-planar
  gemm_xz_k<<<GBZ, b256, 0, stream>>>(x, Wzt, cz, Z, N_NODES);

  // Horner: out = z0 + A(z1 + A(z2 + A(z3 + A z4)))
  agg2_k<0><<<AB12, b256, 0, stream>>>(rowp, csr, nullptr, Zd, ya, nullptr, N_NODES);
  agg2_k<1><<<AB12, b256, 0, stream>>>(rowp, csr, ya, Zd, yb, nullptr, N_NODES);
  agg2_k<2><<<AB12, b256, 0, stream>>>(rowp, csr, yb, Zd, ya, nullptr, N_NODES);
  agg2_k<3><<<AB12, b256, 0, stream>>>(rowp, csr, ya, Zd, nullptr, out, N_NODES);
}